// Round 2
// baseline (632.269 us; speedup 1.0000x reference)
//
#include <hip/hip_runtime.h>
#include <cstddef>

#define HH 1024
#define WW 1024
#define NB 4
#define NK 6
#define NT 128      // threads per block = colsum columns
#define TX 116      // output columns per block (NT - 2*HALO)
#define SY 32       // output rows per block
#define HALO 6      // max (k-1)/2

typedef float f4 __attribute__((ext_vector_type(4)));

__global__ __launch_bounds__(NT)
void fused_box_kernel(const float* __restrict__ xin,
                      const float* __restrict__ fo,
                      float* __restrict__ out)
{
    // colsum exchange buffer: 6 scales x 128 cols x float4 = 12 KB
    __shared__ f4 lds[NK][NT];

    const int t  = threadIdx.x;
    const int x0 = blockIdx.x * TX;
    const int y0 = blockIdx.y * SY;
    const int b  = blockIdx.z;

    const int xc = x0 - HALO + t;                 // this thread's colsum column
    const bool cv = (xc >= 0) && (xc < WW);

    const float* __restrict__ irr = xin + (size_t)b * 6 * HH * WW;   // ch 0..2
    const float* __restrict__ alb = irr + (size_t)3 * HH * WW;       // ch 3..5
    const float* __restrict__ gm  = fo  + (size_t)b * 12 * HH * WW;  // ch 0..5
    const float* __restrict__ alo = gm  + (size_t)NK * HH * WW;      // ch 6..11
    float* __restrict__ o = out + (size_t)b * 3 * HH * WW;

    // running column sums: cs[s] = {sum g, sum g*i0, sum g*i1, sum g*i2}
    f4 cs[NK];
#pragma unroll
    for (int s = 0; s < NK; ++s) cs[s] = (f4)0.0f;

    // ---- warmup: build colsums for output row y0 (rows y0-6 .. y0+6) ----
    if (cv) {
#pragma unroll
        for (int d = -HALO; d <= HALO; ++d) {
            const int ad = d < 0 ? -d : d;
            const int smin = ad > 1 ? ad - 1 : 0;   // scales with p_s >= |d|
            const int r = y0 + d;
            if (r >= 0 && r < HH) {
                const int ro = r * WW + xc;
                const float i0 = irr[ro];
                const float i1 = irr[HH * WW + ro];
                const float i2 = irr[2 * HH * WW + ro];
#pragma unroll
                for (int s = 0; s < NK; ++s) {
                    if (s >= smin) {
                        const float g = __expf(gm[(size_t)s * HH * WW + ro]);
                        cs[s].x += g;
                        cs[s].y += g * i0;
                        cs[s].z += g * i1;
                        cs[s].w += g * i2;
                    }
                }
            }
        }
    }

    const int xo = x0 + t;                        // output column
    const bool ov = (t < TX) && (xo < WW);
    const int yend = y0 + SY;

    for (int y = y0; y < yend; ++y) {
        // ---- publish colsums ----
#pragma unroll
        for (int s = 0; s < NK; ++s) lds[s][t] = cs[s];
        __syncthreads();

        // ---- x-window sums + combine ----
        if (ov) {
            const int ri = y * WW + xo;
            float e[NK];
            float m = -1e30f;
#pragma unroll
            for (int s = 0; s < NK; ++s) {
                e[s] = alo[(size_t)s * HH * WW + ri];
                m = fmaxf(m, e[s]);
            }
            float den = 0.0f;
#pragma unroll
            for (int s = 0; s < NK; ++s) {
                e[s] = __expf(e[s] - m);
                den += e[s];
            }
            float a0 = 0.0f, a1 = 0.0f, a2 = 0.0f;
#pragma unroll
            for (int s = 0; s < NK; ++s) {
                const int p = s + 1;
                f4 wv = lds[s][t + HALO - p];
#pragma unroll
                for (int dx = -p + 1; dx <= p; ++dx)
                    wv += lds[s][t + HALO + dx];
                const float rw = e[s] / wv.x;      // alpha-numerator / wsum
                a0 += rw * wv.y;
                a1 += rw * wv.z;
                a2 += rw * wv.w;
            }
            const float rden = 1.0f / den;
            const float b0 = alb[ri];
            const float b1 = alb[HH * WW + ri];
            const float b2 = alb[2 * HH * WW + ri];
            o[ri]              = a0 * b0 * rden;
            o[HH * WW + ri]    = a1 * b1 * rden;
            o[2 * HH * WW + ri] = a2 * b2 * rden;
        }
        __syncthreads();

        // ---- slide colsums y -> y+1 ----
        if (cv && (y + 1 < yend)) {
            const int yn = y + 1;
#pragma unroll
            for (int s = 0; s < NK; ++s) {
                const int p = s + 1;
                const int rn = yn + p;       // incoming row
                const int rq = yn - p - 1;   // outgoing row
                if (rn < HH) {
                    const int ro = rn * WW + xc;
                    const float g = __expf(gm[(size_t)s * HH * WW + ro]);
                    const float i0 = irr[ro];
                    const float i1 = irr[HH * WW + ro];
                    const float i2 = irr[2 * HH * WW + ro];
                    cs[s].x += g;
                    cs[s].y += g * i0;
                    cs[s].z += g * i1;
                    cs[s].w += g * i2;
                }
                if (rq >= 0) {
                    const int ro = rq * WW + xc;
                    const float g = __expf(gm[(size_t)s * HH * WW + ro]);
                    const float i0 = irr[ro];
                    const float i1 = irr[HH * WW + ro];
                    const float i2 = irr[2 * HH * WW + ro];
                    cs[s].x -= g;
                    cs[s].y -= g * i0;
                    cs[s].z -= g * i1;
                    cs[s].w -= g * i2;
                }
            }
        }
    }
}

extern "C" void kernel_launch(void* const* d_in, const int* in_sizes, int n_in,
                              void* d_out, int out_size, void* d_ws, size_t ws_size,
                              hipStream_t stream)
{
    const float* xin = (const float*)d_in[0];
    const float* fo  = (const float*)d_in[1];
    float* out = (float*)d_out;

    dim3 grid((WW + TX - 1) / TX, HH / SY, NB);
    fused_box_kernel<<<grid, NT, 0, stream>>>(xin, fo, out);
}

// Round 4
// 467.535 us; speedup vs baseline: 1.3523x; 1.3523x over previous
//
#include <hip/hip_runtime.h>
#include <cstddef>

#define HH 1024
#define WW 1024
#define NB 4
#define NK 6
#define NT 128      // threads per block = colsum columns
#define TX 116      // output columns per block (NT - 2*HALO)
#define SY 8        // output rows per block (4x grid vs SY=32 for occupancy)
#define HALO 6      // max (k-1)/2

typedef float f4 __attribute__((ext_vector_type(4)));

__global__ __launch_bounds__(NT)
void fused_box_kernel(const float* __restrict__ xin,
                      const float* __restrict__ fo,
                      float* __restrict__ out)
{
    // colsum exchange buffer: 6 scales x 128 cols x float4 = 12 KB
    __shared__ f4 lds[NK][NT];

    const int t  = threadIdx.x;
    const int x0 = blockIdx.x * TX;
    const int y0 = blockIdx.y * SY;
    const int b  = blockIdx.z;

    const int xc = x0 - HALO + t;                 // this thread's colsum column
    const bool cv = (xc >= 0) && (xc < WW);

    const float* __restrict__ irr = xin + (size_t)b * 6 * HH * WW;   // ch 0..2
    const float* __restrict__ alb = irr + (size_t)3 * HH * WW;       // ch 3..5
    const float* __restrict__ gm  = fo  + (size_t)b * 12 * HH * WW;  // ch 0..5
    const float* __restrict__ alo = gm  + (size_t)NK * HH * WW;      // ch 6..11
    float* __restrict__ o = out + (size_t)b * 3 * HH * WW;

    // running column sums: cs[s] = {sum g, sum g*i0, sum g*i1, sum g*i2}
    f4 cs[NK];
#pragma unroll
    for (int s = 0; s < NK; ++s) cs[s] = (f4)0.0f;

    // ---- warmup: build colsums for output row y0 (rows y0-6 .. y0+6) ----
    if (cv) {
#pragma unroll
        for (int d = -HALO; d <= HALO; ++d) {
            const int ad = d < 0 ? -d : d;
            const int smin = ad > 1 ? ad - 1 : 0;   // scales with p_s >= |d|
            const int r = y0 + d;
            if (r >= 0 && r < HH) {
                const int ro = r * WW + xc;
                const float i0 = irr[ro];
                const float i1 = irr[HH * WW + ro];
                const float i2 = irr[2 * HH * WW + ro];
#pragma unroll
                for (int s = 0; s < NK; ++s) {
                    if (s >= smin) {
                        const float g = __expf(gm[(size_t)s * HH * WW + ro]);
                        cs[s].x += g;
                        cs[s].y += g * i0;
                        cs[s].z += g * i1;
                        cs[s].w += g * i2;
                    }
                }
            }
        }
    }

    const int xo = x0 + t;                        // output column
    const bool ov = (t < TX) && (xo < WW);
    const int yend = y0 + SY;

    for (int y = y0; y < yend; ++y) {
        // ---- publish colsums ----
#pragma unroll
        for (int s = 0; s < NK; ++s) lds[s][t] = cs[s];
        __syncthreads();

        // ---- prefetch slide rows for y+1 (latency hides under compute) ----
        float gin_[NK], gi0[NK], gi1[NK], gi2[NK];
        float gou_[NK], go0[NK], go1[NK], go2[NK];
        bool vin[NK], vou[NK];
        const bool doSlide = cv && (y + 1 < yend);
        if (doSlide) {
            const int yn = y + 1;
#pragma unroll
            for (int s = 0; s < NK; ++s) {
                const int p = s + 1;
                int rn = yn + p;
                vin[s] = rn < HH; rn = vin[s] ? rn : HH - 1;
                int rq = yn - p - 1;
                vou[s] = rq >= 0; rq = vou[s] ? rq : 0;
                const int ron = rn * WW + xc;
                const int roq = rq * WW + xc;
                gin_[s] = gm[(size_t)s * HH * WW + ron];
                gi0[s]  = irr[ron];
                gi1[s]  = irr[HH * WW + ron];
                gi2[s]  = irr[2 * HH * WW + ron];
                gou_[s] = gm[(size_t)s * HH * WW + roq];
                go0[s]  = irr[roq];
                go1[s]  = irr[HH * WW + roq];
                go2[s]  = irr[2 * HH * WW + roq];
            }
        }

        // ---- x-window sums + combine ----
        if (ov) {
            const int ri = y * WW + xo;
            float e[NK];
            float m = -1e30f;
#pragma unroll
            for (int s = 0; s < NK; ++s) {
                e[s] = alo[(size_t)s * HH * WW + ri];
                m = fmaxf(m, e[s]);
            }
            float den = 0.0f;
#pragma unroll
            for (int s = 0; s < NK; ++s) {
                e[s] = __expf(e[s] - m);
                den += e[s];
            }
            float a0 = 0.0f, a1 = 0.0f, a2 = 0.0f;
#pragma unroll
            for (int s = 0; s < NK; ++s) {
                const int p = s + 1;
                f4 wv = lds[s][t + HALO - p];
#pragma unroll
                for (int dx = -p + 1; dx <= p; ++dx)
                    wv += lds[s][t + HALO + dx];
                const float rw = e[s] / wv.x;      // alpha-numerator / wsum
                a0 += rw * wv.y;
                a1 += rw * wv.z;
                a2 += rw * wv.w;
            }
            const float rden = 1.0f / den;
            const float b0 = alb[ri];
            const float b1 = alb[HH * WW + ri];
            const float b2 = alb[2 * HH * WW + ri];
            o[ri]               = a0 * b0 * rden;
            o[HH * WW + ri]     = a1 * b1 * rden;
            o[2 * HH * WW + ri] = a2 * b2 * rden;
        }

        // ---- apply slide updates (loads already in flight) ----
        if (doSlide) {
#pragma unroll
            for (int s = 0; s < NK; ++s) {
                const float w = vin[s] ? __expf(gin_[s]) : 0.0f;
                cs[s].x += w;
                cs[s].y += w * gi0[s];
                cs[s].z += w * gi1[s];
                cs[s].w += w * gi2[s];
                const float u = vou[s] ? __expf(gou_[s]) : 0.0f;
                cs[s].x -= u;
                cs[s].y -= u * go0[s];
                cs[s].z -= u * go1[s];
                cs[s].w -= u * go2[s];
            }
        }
        __syncthreads();
    }
}

extern "C" void kernel_launch(void* const* d_in, const int* in_sizes, int n_in,
                              void* d_out, int out_size, void* d_ws, size_t ws_size,
                              hipStream_t stream)
{
    const float* xin = (const float*)d_in[0];
    const float* fo  = (const float*)d_in[1];
    float* out = (float*)d_out;

    dim3 grid((WW + TX - 1) / TX, HH / SY, NB);
    fused_box_kernel<<<grid, NT, 0, stream>>>(xin, fo, out);
}

// Round 5
// 458.772 us; speedup vs baseline: 1.3782x; 1.0191x over previous
//
#include <hip/hip_runtime.h>
#include <cstddef>

#define HH 1024
#define WW 1024
#define HW (HH * WW)
#define NB 4
#define NK 6
#define NT 64       // threads per block = ONE wave (barrier-free block)
#define NC 128      // colsum columns per block (2 per thread)
#define TX 116      // output columns per block (NC - 2*HALO)
#define SY 8        // output rows per block
#define HALO 6      // max (k-1)/2

typedef float f2 __attribute__((ext_vector_type(2)));
typedef float f4 __attribute__((ext_vector_type(4)));

__device__ __forceinline__ f2 ld2(const float* p) { return *reinterpret_cast<const f2*>(p); }

__global__ __launch_bounds__(NT)
void fused_box_kernel(const float* __restrict__ xin,
                      const float* __restrict__ fo,
                      float* __restrict__ out)
{
    // colsum exchange: 6 scales x 128 cols x float4 = 12 KB
    __shared__ f4 lds[NK][NC];

    const int t  = threadIdx.x;
    const int x0 = blockIdx.x * TX;
    const int y0 = blockIdx.y * SY;
    const int b  = blockIdx.z;

    const float* __restrict__ irr = xin + (size_t)b * 6 * HW;   // ch 0..2
    const float* __restrict__ alb = irr + (size_t)3 * HW;       // ch 3..5
    const float* __restrict__ gm  = fo  + (size_t)b * 12 * HW;  // ch 0..5
    const float* __restrict__ alo = gm  + (size_t)NK * HW;      // ch 6..11
    float* __restrict__ o = out + (size_t)b * 3 * HW;

    // this thread's slide column pair: c0, c0+1 (c0 even -> 8B-aligned f2)
    const int c0  = x0 - HALO + 2 * t;
    const int cc  = min(max(c0, 0), WW - 2);
    const float mx0 = (c0 >= 0 && c0 < WW) ? 1.0f : 0.0f;
    const float mx1 = (c0 + 1 >= 0 && c0 + 1 < WW) ? 1.0f : 0.0f;

    // running column sums per scale: {sum g, sum g*i0, sum g*i1, sum g*i2}
    f4 csA[NK], csB[NK];
#pragma unroll
    for (int s = 0; s < NK; ++s) { csA[s] = (f4)0.0f; csB[s] = (f4)0.0f; }

    // ---- warmup: colsums for output row y0 (rows y0-6 .. y0+6) ----
#pragma unroll
    for (int d = -HALO; d <= HALO; ++d) {
        const int ad = d < 0 ? -d : d;
        const int smin = ad > 1 ? ad - 1 : 0;
        const int r  = y0 + d;
        const float rv = (r >= 0 && r < HH) ? 1.0f : 0.0f;
        const int rc = min(max(r, 0), HH - 1);
        const int ro = rc * WW + cc;
        const f2 i0 = ld2(irr + ro);
        const f2 i1 = ld2(irr + HW + ro);
        const f2 i2 = ld2(irr + 2 * HW + ro);
        const float w0 = rv * mx0, w1 = rv * mx1;
#pragma unroll
        for (int s = 0; s < NK; ++s) {
            if (s >= smin) {
                const f2 gr = ld2(gm + s * HW + ro);
                const float ga = __expf(gr.x) * w0;
                const float gb = __expf(gr.y) * w1;
                csA[s].x += ga; csA[s].y += ga * i0.x; csA[s].z += ga * i1.x; csA[s].w += ga * i2.x;
                csB[s].x += gb; csB[s].y += gb * i0.y; csB[s].z += gb * i1.y; csB[s].w += gb * i2.y;
            }
        }
    }

    // window/output columns: xA = x0+t (always valid), xB = x0+64+t (guarded)
    const int xA = x0 + t;
    const int xB = x0 + 64 + t;
    const bool bv = (64 + t < TX) && (xB < WW);
    const int yend = y0 + SY;

#pragma unroll 1
    for (int y = y0; y < yend; ++y) {
        // ---- publish colsums (single wave: no s_barrier needed) ----
#pragma unroll
        for (int s = 0; s < NK; ++s) {
            lds[s][2 * t]     = csA[s];
            lds[s][2 * t + 1] = csB[s];
        }
        asm volatile("s_waitcnt lgkmcnt(0)" ::: "memory");
        __builtin_amdgcn_sched_barrier(0);

        // ---- issue next-row slide loads + this row's alo/alb loads NOW ----
        // (unconditional, clamped addresses; validity folded into g-masks)
        const int yn = y + 1;
        f2 gin[NK], gi0[NK], gi1[NK], gi2[NK];
        f2 gou[NK], go0[NK], go1[NK], go2[NK];
        float win[NK], wou[NK];
#pragma unroll
        for (int s = 0; s < NK; ++s) {
            const int p = s + 1;
            const int rn = yn + p;
            win[s] = (rn < HH) ? 1.0f : 0.0f;
            const int ron = min(rn, HH - 1) * WW + cc;
            const int rq = yn - p - 1;
            wou[s] = (rq >= 0) ? 1.0f : 0.0f;
            const int roq = max(rq, 0) * WW + cc;
            gin[s] = ld2(gm + s * HW + ron);
            gi0[s] = ld2(irr + ron);
            gi1[s] = ld2(irr + HW + ron);
            gi2[s] = ld2(irr + 2 * HW + ron);
            gou[s] = ld2(gm + s * HW + roq);
            go0[s] = ld2(irr + roq);
            go1[s] = ld2(irr + HW + roq);
            go2[s] = ld2(irr + 2 * HW + roq);
        }
        const int riA = y * WW + xA;
        float eA[NK];
#pragma unroll
        for (int s = 0; s < NK; ++s) eA[s] = alo[s * HW + riA];
        const float bA0 = alb[riA];
        const float bA1 = alb[HW + riA];
        const float bA2 = alb[2 * HW + riA];
        const int riB = y * WW + (bv ? xB : xA);
        float eB[NK];
#pragma unroll
        for (int s = 0; s < NK; ++s) eB[s] = alo[s * HW + riB];
        const float bB0 = alb[riB];
        const float bB1 = alb[HW + riB];
        const float bB2 = alb[2 * HW + riB];
        __builtin_amdgcn_sched_barrier(0);   // pin: loads issue before window phase

        // ---- column A: softmax + x-window sums + output ----
        {
            float m = -1e30f;
#pragma unroll
            for (int s = 0; s < NK; ++s) m = fmaxf(m, eA[s]);
            float den = 0.0f;
            float ex[NK];
#pragma unroll
            for (int s = 0; s < NK; ++s) { ex[s] = __expf(eA[s] - m); den += ex[s]; }
            float a0 = 0.0f, a1 = 0.0f, a2 = 0.0f;
#pragma unroll
            for (int s = 0; s < NK; ++s) {
                const int p = s + 1;
                f4 wv = lds[s][t + HALO - p];
#pragma unroll
                for (int dx = -p + 1; dx <= p; ++dx)
                    wv += lds[s][t + HALO + dx];
                const float rw = ex[s] / wv.x;
                a0 += rw * wv.y; a1 += rw * wv.z; a2 += rw * wv.w;
            }
            const float rden = 1.0f / den;
            o[riA]            = a0 * bA0 * rden;
            o[HW + riA]       = a1 * bA1 * rden;
            o[2 * HW + riA]   = a2 * bA2 * rden;
        }

        // ---- column B (lanes with a second valid output column) ----
        if (bv) {
            float m = -1e30f;
#pragma unroll
            for (int s = 0; s < NK; ++s) m = fmaxf(m, eB[s]);
            float den = 0.0f;
            float ex[NK];
#pragma unroll
            for (int s = 0; s < NK; ++s) { ex[s] = __expf(eB[s] - m); den += ex[s]; }
            float a0 = 0.0f, a1 = 0.0f, a2 = 0.0f;
#pragma unroll
            for (int s = 0; s < NK; ++s) {
                const int p = s + 1;
                f4 wv = lds[s][t + 64 + HALO - p];
#pragma unroll
                for (int dx = -p + 1; dx <= p; ++dx)
                    wv += lds[s][t + 64 + HALO + dx];
                const float rw = ex[s] / wv.x;
                a0 += rw * wv.y; a1 += rw * wv.z; a2 += rw * wv.w;
            }
            const float rden = 1.0f / den;
            o[riB]            = a0 * bB0 * rden;
            o[HW + riB]       = a1 * bB1 * rden;
            o[2 * HW + riB]   = a2 * bB2 * rden;
        }

        // ---- apply slide updates (loads long in flight); last iter harmless ----
#pragma unroll
        for (int s = 0; s < NK; ++s) {
            const float ga = __expf(gin[s].x) * win[s] * mx0;
            const float gb = __expf(gin[s].y) * win[s] * mx1;
            csA[s].x += ga; csA[s].y += ga * gi0[s].x; csA[s].z += ga * gi1[s].x; csA[s].w += ga * gi2[s].x;
            csB[s].x += gb; csB[s].y += gb * gi0[s].y; csB[s].z += gb * gi1[s].y; csB[s].w += gb * gi2[s].y;
            const float ua = __expf(gou[s].x) * wou[s] * mx0;
            const float ub = __expf(gou[s].y) * wou[s] * mx1;
            csA[s].x -= ua; csA[s].y -= ua * go0[s].x; csA[s].z -= ua * go1[s].x; csA[s].w -= ua * go2[s].x;
            csB[s].x -= ub; csB[s].y -= ub * go0[s].y; csB[s].z -= ub * go1[s].y; csB[s].w -= ub * go2[s].y;
        }
    }
}

extern "C" void kernel_launch(void* const* d_in, const int* in_sizes, int n_in,
                              void* d_out, int out_size, void* d_ws, size_t ws_size,
                              hipStream_t stream)
{
    const float* xin = (const float*)d_in[0];
    const float* fo  = (const float*)d_in[1];
    float* out = (float*)d_out;

    dim3 grid((WW + TX - 1) / TX, HH / SY, NB);
    fused_box_kernel<<<grid, NT, 0, stream>>>(xin, fo, out);
}

// Round 8
// 431.479 us; speedup vs baseline: 1.4654x; 1.0633x over previous
//
#include <hip/hip_runtime.h>
#include <cstddef>

#define HH 1024
#define WW 1024
#define HW (HH * WW)
#define NB 4
#define NK 6
#define NT 128      // threads per block (2 waves) = colsum columns
#define TX 116      // output columns per block (NT - 2*HALO)
#define SY 16       // output rows per block
#define HALO 6      // max (k-1)/2
#define YBLK (HH / SY)          // 64 block-rows
#define YPX (YBLK / 8)          // 8 block-rows per XCD band

typedef float f4 __attribute__((ext_vector_type(4)));

__global__ __launch_bounds__(NT, 4)
void fused_box_kernel(const float* __restrict__ xin,
                      const float* __restrict__ fo,
                      float* __restrict__ out)
{
    // colsum exchange buffer: 6 scales x 128 cols x float4 = 12 KB
    __shared__ f4 lds[NK][NT];

    // ---- XCD y-band swizzle: wg w -> XCD q=w%8 owns 8 consecutive block-rows
    // per (x,b); y-adjacent blocks are consecutive in dispatch on the same XCD
    const int w = blockIdx.x;
    const int q  = w & 7;          // implicit XCD (round-robin dispatch)
    const int j  = w >> 3;         // 0..287 = 8(y) * 9(x) * 4(b)
    const int yl = j & 7;
    const int xb = (j >> 3) % 9;
    const int b  = j / 72;
    const int y0 = (q * YPX + yl) * SY;
    const int x0 = xb * TX;

    const int t  = threadIdx.x;
    const int xc = x0 - HALO + t;                 // this thread's colsum column
    const int cc = min(max(xc, 0), WW - 1);       // clamped (for early loads)
    const float mx = (xc >= 0 && xc < WW) ? 1.0f : 0.0f;

    const float* __restrict__ irr = xin + (size_t)b * 6 * HW;   // ch 0..2
    const float* __restrict__ alb = irr + (size_t)3 * HW;       // ch 3..5
    const float* __restrict__ gm  = fo  + (size_t)b * 12 * HW;  // ch 0..5
    const float* __restrict__ alo = gm  + (size_t)NK * HW;      // ch 6..11
    float* __restrict__ o = out + (size_t)b * 3 * HW;

    // running column sums: cs[s] = {sum g, sum g*i0, sum g*i1, sum g*i2}
    f4 cs[NK];
#pragma unroll
    for (int s = 0; s < NK; ++s) cs[s] = (f4)0.0f;

    // ---- warmup: build colsums for output row y0 (rows y0-6 .. y0+6) ----
    if (mx != 0.0f) {
#pragma unroll
        for (int d = -HALO; d <= HALO; ++d) {
            const int ad = d < 0 ? -d : d;
            const int smin = ad > 1 ? ad - 1 : 0;   // scales with p_s >= |d|
            const int r = y0 + d;
            if (r >= 0 && r < HH) {
                const int ro = r * WW + cc;
                const float i0 = irr[ro];
                const float i1 = irr[HW + ro];
                const float i2 = irr[2 * HW + ro];
#pragma unroll
                for (int s = 0; s < NK; ++s) {
                    if (s >= smin) {
                        const float g = __expf(gm[(size_t)s * HW + ro]);
                        cs[s].x += g;
                        cs[s].y += g * i0;
                        cs[s].z += g * i1;
                        cs[s].w += g * i2;
                    }
                }
            }
        }
    }

    const int xo = x0 + t;                        // output column
    const bool ov = (t < TX) && (xo < WW);
    const int xq = min(xo, WW - 1);               // clamped for early loads
    const int yend = y0 + SY;

#pragma unroll 1
    for (int y = y0; y < yend; ++y) {
        // ---- publish colsums (stride-16B per lane: conflict-free, as R4) ----
#pragma unroll
        for (int s = 0; s < NK; ++s) lds[s][t] = cs[s];
        __syncthreads();

        // ---- issue ALL of this step's global loads NOW (clamped+masked),
        //      pinned before the window phase so latency hides under it ----
        const int yn = y + 1;
        float gin[NK], gi0[NK], gi1[NK], gi2[NK];
        float gou[NK], go0[NK], go1[NK], go2[NK];
        float win[NK], wou[NK];
#pragma unroll
        for (int s = 0; s < NK; ++s) {
            const int p = s + 1;
            const int rn = yn + p;
            win[s] = (rn < HH) ? 1.0f : 0.0f;
            const int ron = min(rn, HH - 1) * WW + cc;
            const int rq = yn - p - 1;
            wou[s] = (rq >= 0) ? 1.0f : 0.0f;
            const int roq = max(rq, 0) * WW + cc;
            gin[s] = gm[(size_t)s * HW + ron];
            gi0[s] = irr[ron];
            gi1[s] = irr[HW + ron];
            gi2[s] = irr[2 * HW + ron];
            gou[s] = gm[(size_t)s * HW + roq];
            go0[s] = irr[roq];
            go1[s] = irr[HW + roq];
            go2[s] = irr[2 * HW + roq];
        }
        const int ri = y * WW + xq;
        float e[NK];
#pragma unroll
        for (int s = 0; s < NK; ++s) e[s] = alo[(size_t)s * HW + ri];
        const float b0 = alb[ri];
        const float b1 = alb[HW + ri];
        const float b2 = alb[2 * HW + ri];
        __builtin_amdgcn_sched_barrier(0);   // pin: loads issue before this point

        // ---- x-window sums + softmax + combine + store ----
        if (ov) {
            float m = -1e30f;
#pragma unroll
            for (int s = 0; s < NK; ++s) m = fmaxf(m, e[s]);
            float den = 0.0f;
            float ex[NK];
#pragma unroll
            for (int s = 0; s < NK; ++s) { ex[s] = __expf(e[s] - m); den += ex[s]; }
            float a0 = 0.0f, a1 = 0.0f, a2 = 0.0f;
#pragma unroll
            for (int s = 0; s < NK; ++s) {
                const int p = s + 1;
                f4 wv = lds[s][t + HALO - p];
#pragma unroll
                for (int dx = -p + 1; dx <= p; ++dx)
                    wv += lds[s][t + HALO + dx];
                const float rw = ex[s] / wv.x;     // alpha-numerator / wsum
                a0 += rw * wv.y;
                a1 += rw * wv.z;
                a2 += rw * wv.w;
            }
            const float rden = 1.0f / den;
            o[ri]            = a0 * b0 * rden;
            o[HW + ri]       = a1 * b1 * rden;
            o[2 * HW + ri]   = a2 * b2 * rden;
        }

        // ---- apply slide updates (loads long in flight); masks fold edges ----
#pragma unroll
        for (int s = 0; s < NK; ++s) {
            const float ga = __expf(gin[s]) * win[s] * mx;
            cs[s].x += ga; cs[s].y += ga * gi0[s]; cs[s].z += ga * gi1[s]; cs[s].w += ga * gi2[s];
            const float ua = __expf(gou[s]) * wou[s] * mx;
            cs[s].x -= ua; cs[s].y -= ua * go0[s]; cs[s].z -= ua * go1[s]; cs[s].w -= ua * go2[s];
        }
        __syncthreads();
    }
}

extern "C" void kernel_launch(void* const* d_in, const int* in_sizes, int n_in,
                              void* d_out, int out_size, void* d_ws, size_t ws_size,
                              hipStream_t stream)
{
    const float* xin = (const float*)d_in[0];
    const float* fo  = (const float*)d_in[1];
    float* out = (float*)d_out;

    // 1-D grid so the wgid%8 XCD round-robin can be exploited: 8 * 8 * 9 * 4
    fused_box_kernel<<<dim3(8 * YPX * 9 * NB), NT, 0, stream>>>(xin, fo, out);
}

// Round 11
// 422.787 us; speedup vs baseline: 1.4955x; 1.0206x over previous
//
#include <hip/hip_runtime.h>
#include <cstddef>

#define HH 1024
#define WW 1024
#define HW (HH * WW)
#define NB 4
#define NK 6
#define NT 128      // threads per block (2 waves) = colsum columns
#define TX 116      // output columns per block (NT - 2*HALO)
#define SY 16       // output rows per block
#define HALO 6      // max (k-1)/2
#define YBLK (HH / SY)          // 64 block-rows
#define YPX (YBLK / 8)          // 8 block-rows per XCD band

typedef float f4 __attribute__((ext_vector_type(4)));

__global__ __launch_bounds__(NT, 3)
void fused_box_kernel(const float* __restrict__ xin,
                      const float* __restrict__ fo,
                      float* __restrict__ out)
{
    // DOUBLE-BUFFERED colsum exchange: 2 x 6 scales x 128 cols x f4 = 24 KB.
    // One barrier per row: a wave reading buf[pb] in iter y must reach iter
    // y+1's barrier before any wave can reach iter y+2's writes of buf[pb].
    __shared__ f4 lds[2][NK][NT];

    // ---- XCD y-band swizzle (validated R8: FETCH 590->490 MB) ----
    const int w = blockIdx.x;
    const int q  = w & 7;          // implicit XCD (round-robin dispatch)
    const int j  = w >> 3;         // 0..287 = 8(y) * 9(x) * 4(b)
    const int yl = j & 7;
    const int xb = (j >> 3) % 9;
    const int b  = j / 72;
    const int y0 = (q * YPX + yl) * SY;
    const int x0 = xb * TX;

    const int t  = threadIdx.x;
    const int xc = x0 - HALO + t;                 // this thread's colsum column
    const int cc = min(max(xc, 0), WW - 1);       // clamped (for early loads)
    const float mx = (xc >= 0 && xc < WW) ? 1.0f : 0.0f;

    const float* __restrict__ irr = xin + (size_t)b * 6 * HW;   // ch 0..2
    const float* __restrict__ alb = irr + (size_t)3 * HW;       // ch 3..5
    const float* __restrict__ gm  = fo  + (size_t)b * 12 * HW;  // ch 0..5
    const float* __restrict__ alo = gm  + (size_t)NK * HW;      // ch 6..11
    float* __restrict__ o = out + (size_t)b * 3 * HW;

    // running column sums: cs[s] = {sum g, sum g*i0, sum g*i1, sum g*i2}
    f4 cs[NK];
#pragma unroll
    for (int s = 0; s < NK; ++s) cs[s] = (f4)0.0f;

    // ---- warmup: build colsums for output row y0 (rows y0-6 .. y0+6) ----
    if (mx != 0.0f) {
#pragma unroll
        for (int d = -HALO; d <= HALO; ++d) {
            const int ad = d < 0 ? -d : d;
            const int smin = ad > 1 ? ad - 1 : 0;   // scales with p_s >= |d|
            const int r = y0 + d;
            if (r >= 0 && r < HH) {
                const int ro = r * WW + cc;
                const float i0 = irr[ro];
                const float i1 = irr[HW + ro];
                const float i2 = irr[2 * HW + ro];
#pragma unroll
                for (int s = 0; s < NK; ++s) {
                    if (s >= smin) {
                        const float g = __expf(gm[(size_t)s * HW + ro]);
                        cs[s].x += g;
                        cs[s].y += g * i0;
                        cs[s].z += g * i1;
                        cs[s].w += g * i2;
                    }
                }
            }
        }
    }

    const int xo = x0 + t;                        // output column
    const bool ov = (t < TX) && (xo < WW);
    const int xq = min(xo, WW - 1);               // clamped for early loads
    const int yend = y0 + SY;

#pragma unroll 1
    for (int y = y0; y < yend; ++y) {
        const int pb = y & 1;                     // publish/read buffer

        // ---- A: issue ALL global loads for this step NOW (clamped+masked):
        //      slide rows for y+1, alo/alb for row y. They stay IN FLIGHT
        //      across the (lgkm-only) barrier and the whole window phase. ----
        const int yn = y + 1;
        float gin[NK], gi0[NK], gi1[NK], gi2[NK];
        float gou[NK], go0[NK], go1[NK], go2[NK];
        float win[NK], wou[NK];
#pragma unroll
        for (int s = 0; s < NK; ++s) {
            const int p = s + 1;
            const int rn = yn + p;
            win[s] = (rn < HH) ? 1.0f : 0.0f;
            const int ron = min(rn, HH - 1) * WW + cc;
            const int rq = yn - p - 1;
            wou[s] = (rq >= 0) ? 1.0f : 0.0f;
            const int roq = max(rq, 0) * WW + cc;
            gin[s] = gm[(size_t)s * HW + ron];
            gi0[s] = irr[ron];
            gi1[s] = irr[HW + ron];
            gi2[s] = irr[2 * HW + ron];
            gou[s] = gm[(size_t)s * HW + roq];
            go0[s] = irr[roq];
            go1[s] = irr[HW + roq];
            go2[s] = irr[2 * HW + roq];
        }
        const int ri = y * WW + xq;
        float e[NK];
#pragma unroll
        for (int s = 0; s < NK; ++s) e[s] = alo[(size_t)s * HW + ri];
        const float b0 = alb[ri];
        const float b1 = alb[HW + ri];
        const float b2 = alb[2 * HW + ri];
        __builtin_amdgcn_sched_barrier(0);   // loads issue before this point

        // ---- B: publish colsums; barrier waits LDS only (vmem stays in flight)
#pragma unroll
        for (int s = 0; s < NK; ++s) lds[pb][s][t] = cs[s];
        asm volatile("s_waitcnt lgkmcnt(0)" ::: "memory");
        __builtin_amdgcn_sched_barrier(0);
        __builtin_amdgcn_s_barrier();
        __builtin_amdgcn_sched_barrier(0);

        // ---- C: x-window sums + softmax + combine + store ----
        if (ov) {
            float m = -1e30f;
#pragma unroll
            for (int s = 0; s < NK; ++s) m = fmaxf(m, e[s]);
            float den = 0.0f;
            float ex[NK];
#pragma unroll
            for (int s = 0; s < NK; ++s) { ex[s] = __expf(e[s] - m); den += ex[s]; }
            float a0 = 0.0f, a1 = 0.0f, a2 = 0.0f;
#pragma unroll
            for (int s = 0; s < NK; ++s) {
                const int p = s + 1;
                f4 wv = lds[pb][s][t + HALO - p];
#pragma unroll
                for (int dx = -p + 1; dx <= p; ++dx)
                    wv += lds[pb][s][t + HALO + dx];
                const float rw = ex[s] / wv.x;     // alpha-numerator / wsum
                a0 += rw * wv.y;
                a1 += rw * wv.z;
                a2 += rw * wv.w;
            }
            const float rden = 1.0f / den;
            o[ri]            = a0 * b0 * rden;
            o[HW + ri]       = a1 * b1 * rden;
            o[2 * HW + ri]   = a2 * b2 * rden;
        }
        __builtin_amdgcn_sched_barrier(0);   // D must NOT hoist above C

        // ---- D: apply slide updates (loads were in flight all through C) ----
#pragma unroll
        for (int s = 0; s < NK; ++s) {
            const float ga = __expf(gin[s]) * win[s] * mx;
            cs[s].x += ga; cs[s].y += ga * gi0[s]; cs[s].z += ga * gi1[s]; cs[s].w += ga * gi2[s];
            const float ua = __expf(gou[s]) * wou[s] * mx;
            cs[s].x -= ua; cs[s].y -= ua * go0[s]; cs[s].z -= ua * go1[s]; cs[s].w -= ua * go2[s];
        }
        // no second __syncthreads(): double-buffered LDS makes it redundant
    }
}

extern "C" void kernel_launch(void* const* d_in, const int* in_sizes, int n_in,
                              void* d_out, int out_size, void* d_ws, size_t ws_size,
                              hipStream_t stream)
{
    const float* xin = (const float*)d_in[0];
    const float* fo  = (const float*)d_in[1];
    float* out = (float*)d_out;

    // 1-D grid so the wgid%8 XCD round-robin can be exploited: 8 * 8 * 9 * 4
    fused_box_kernel<<<dim3(8 * YPX * 9 * NB), NT, 0, stream>>>(xin, fo, out);
}